// Round 13
// baseline (3422.430 us; speedup 1.0000x reference)
//
#include <hip/hip_runtime.h>

// LiquidNeuralNetwork: B=512, S=1024, IN=16, HID=64, OUT=1, N_SUB=4 (RK4).
// Batch-parallel MFMA formulation. Workgroup = 4 waves = 16 chains (batch
// columns); wave w owns hidden rows 16w..16w+15 in MFMA C-layout
// (col=lane&15=batch n, row=4*quad+reg -- m89-verified). Per eval:
//   4x tanh -> 1 ds_write_b64 -> __syncthreads -> 2 ds_read_b128 (B-frags)
//   -> 2 chained v_mfma_f32_16x16x32_f16 (A = W_hh*rtau rows, f16, resident)
// The LDS broadcast + barrier cost is amortized over 16 chains (vs 1 before).
// Seed C = (c-y)*rtau; c computed f32 per step from (W_ih@W_in) rows.
// Output dot fused on resident B-frags (8 fdot2 + 2 shfl_xor); out[0] falls
// out of the zero-primed fragments (tanh(0)=0). dt constant (linspace).
// 32 blocks x 256 threads. Wall = 16368 x T_body(~260cyc for 16 chain-evals).

constexpr int SLEN = 1024;
constexpr int INF  = 16;

typedef _Float16 half8 __attribute__((ext_vector_type(8)));
typedef __fp16 h2_t __attribute__((ext_vector_type(2)));
typedef float f32x4 __attribute__((ext_vector_type(4)));

__device__ __forceinline__ float fast_tanh(float x) {
    // tanh(x) = 1 - 2/(e^{2x}+1); exact limits at +/-inf.
    float e = __builtin_amdgcn_exp2f(x * 2.8853900817779268f); // 2*log2(e)
    float r = __builtin_amdgcn_rcpf(e + 1.0f);
    return fmaf(-2.0f, r, 1.0f);
}

__device__ __forceinline__ unsigned pk(float a, float b) {
    return __builtin_bit_cast(unsigned, __builtin_amdgcn_cvt_pkrtz(a, b));
}

__global__ __launch_bounds__(256, 1) void lnn_mfma_kernel(
    const float* __restrict__ x,
    const float* __restrict__ W_in,
    const float* __restrict__ b_in,
    const float* __restrict__ W_hh,
    const float* __restrict__ W_ih,
    const float* __restrict__ bias,
    const float* __restrict__ tau,
    const float* __restrict__ W_out,
    const float* __restrict__ b_out,
    float* __restrict__ out)
{
    const int tid  = threadIdx.x;
    const int w    = tid >> 6;          // wave: hidden row-block 16w..16w+15
    const int lane = tid & 63;
    const int q    = lane >> 4;         // quad
    const int n    = lane & 15;         // batch column within the block
    const int nb   = blockIdx.x * 16 + n;

    // t broadcast: [buf][batch n][hid], f16, row stride 144B (128 data + 16 pad)
    __shared__ __align__(16) unsigned char tbuf[2][16 * 144];

    // ---- A-fragments: W_hh[m][k]*rtau[m], m = 16w + (lane&15), k = 8q+j ----
    const int ia = 16 * w + n;
    const float rta = 1.0f / tau[ia];
    half8 A0, A1;
    {
        const float* wr = W_hh + ia * 64;
        float4 u0 = *(const float4*)(wr + 8 * q);
        float4 u1 = *(const float4*)(wr + 8 * q + 4);
        uint4 t0; t0.x = pk(u0.x*rta, u0.y*rta); t0.y = pk(u0.z*rta, u0.w*rta);
                  t0.z = pk(u1.x*rta, u1.y*rta); t0.w = pk(u1.z*rta, u1.w*rta);
        A0 = __builtin_bit_cast(half8, t0);
        float4 v0 = *(const float4*)(wr + 32 + 8 * q);
        float4 v1 = *(const float4*)(wr + 32 + 8 * q + 4);
        uint4 t1; t1.x = pk(v0.x*rta, v0.y*rta); t1.y = pk(v0.z*rta, v0.w*rta);
                  t1.z = pk(v1.x*rta, v1.y*rta); t1.w = pk(v1.z*rta, v1.w*rta);
        A1 = __builtin_bit_cast(half8, t1);
    }
    // ---- W_out fragments matching B-frag layout (hid = 8q+j / 32+8q+j) ----
    h2_t wo0[4], wo1[4];
    {
        float4 u0 = *(const float4*)(W_out + 8 * q);
        float4 u1 = *(const float4*)(W_out + 8 * q + 4);
        wo0[0] = __builtin_amdgcn_cvt_pkrtz(u0.x, u0.y);
        wo0[1] = __builtin_amdgcn_cvt_pkrtz(u0.z, u0.w);
        wo0[2] = __builtin_amdgcn_cvt_pkrtz(u1.x, u1.y);
        wo0[3] = __builtin_amdgcn_cvt_pkrtz(u1.z, u1.w);
        float4 v0 = *(const float4*)(W_out + 32 + 8 * q);
        float4 v1 = *(const float4*)(W_out + 32 + 8 * q + 4);
        wo1[0] = __builtin_amdgcn_cvt_pkrtz(v0.x, v0.y);
        wo1[1] = __builtin_amdgcn_cvt_pkrtz(v0.z, v0.w);
        wo1[2] = __builtin_amdgcn_cvt_pkrtz(v1.x, v1.y);
        wo1[3] = __builtin_amdgcn_cvt_pkrtz(v1.z, v1.w);
    }
    // ---- per-C-row constants: rows ic = 16w + 4q + r ----
    float rtau_c[4], cbase_rt[4], Wc_rt[4][INF];
    #pragma unroll
    for (int r = 0; r < 4; ++r) {
        const int ic = 16 * w + 4 * q + r;
        const float rt = 1.0f / tau[ic];
        rtau_c[r] = rt;
        float acc[INF];
        #pragma unroll
        for (int k = 0; k < INF; ++k) acc[k] = 0.0f;
        float bc = 0.0f;
        for (int j = 0; j < 64; ++j) {
            float wij = W_ih[ic * 64 + j];
            bc = fmaf(wij, b_in[j], bc);
            #pragma unroll
            for (int k = 0; k < INF; ++k) acc[k] = fmaf(wij, W_in[j*INF + k], acc[k]);
        }
        #pragma unroll
        for (int k = 0; k < INF; ++k) Wc_rt[r][k] = acc[k] * rt;
        cbase_rt[r] = (bc + bias[ic]) * rt;
    }
    const float bo = b_out[0];

    const float hsub  = (1.0f / 1023.0f) * 0.25f;
    const float hsubh = 0.5f * hsub;
    const float h6    = hsub * (1.0f / 6.0f);

    float h[4] = {0,0,0,0}, y[4] = {0,0,0,0}, ks[4], cr[4];
    uint4 z4; z4.x = z4.y = z4.z = z4.w = 0u;
    half8 B0 = __builtin_bit_cast(half8, z4);     // tanh(h=0) = 0
    half8 B1 = B0;

    const float4* xrow = (const float4*)(x + (size_t)nb * SLEN * INF);
    float* orow = out + (size_t)nb * SLEN;

    const int woff  = n * 144 + 32 * w + 8 * q;   // own 4 t values (b64)
    const int roff0 = n * 144 + 16 * q;           // B0: hid 8q..8q+7
    const int roff1 = n * 144 + 64 + 16 * q;      // B1: hid 32+8q..+7

    int p = 0;

    // one eval of all 16 chains; e = RK4 stage, fuse = emit out[s-1]
    auto body = [&](int e, bool fuse, int s) {
        f32x4 seed;
        seed[0] = fmaf(-rtau_c[0], y[0], cr[0]);
        seed[1] = fmaf(-rtau_c[1], y[1], cr[1]);
        seed[2] = fmaf(-rtau_c[2], y[2], cr[2]);
        seed[3] = fmaf(-rtau_c[3], y[3], cr[3]);
        f32x4 f = __builtin_amdgcn_mfma_f32_16x16x32_f16(A0, B0, seed, 0, 0, 0);
        f       = __builtin_amdgcn_mfma_f32_16x16x32_f16(A1, B1, f,    0, 0, 0);
        if (fuse) {                     // out[s-1] from resident B-frags
            uint4 b0 = __builtin_bit_cast(uint4, B0);
            uint4 b1 = __builtin_bit_cast(uint4, B1);
            float o;
            o = __builtin_amdgcn_fdot2(__builtin_bit_cast(h2_t, b0.x), wo0[0], 0.0f, false);
            o = __builtin_amdgcn_fdot2(__builtin_bit_cast(h2_t, b0.y), wo0[1], o, false);
            o = __builtin_amdgcn_fdot2(__builtin_bit_cast(h2_t, b0.z), wo0[2], o, false);
            o = __builtin_amdgcn_fdot2(__builtin_bit_cast(h2_t, b0.w), wo0[3], o, false);
            o = __builtin_amdgcn_fdot2(__builtin_bit_cast(h2_t, b1.x), wo1[0], o, false);
            o = __builtin_amdgcn_fdot2(__builtin_bit_cast(h2_t, b1.y), wo1[1], o, false);
            o = __builtin_amdgcn_fdot2(__builtin_bit_cast(h2_t, b1.z), wo1[2], o, false);
            o = __builtin_amdgcn_fdot2(__builtin_bit_cast(h2_t, b1.w), wo1[3], o, false);
            o += __shfl_xor(o, 16, 64);
            o += __shfl_xor(o, 32, 64);
            if (tid < 16) out[(size_t)(blockIdx.x*16 + tid) * SLEN + (s-1)] = o + bo;
        }
        #pragma unroll
        for (int r = 0; r < 4; ++r) {
            float fr = f[r];
            if (e == 0)      { ks[r] = fr;                   y[r] = fmaf(hsubh, fr, h[r]); }
            else if (e == 1) { ks[r] = fmaf(2.0f, fr, ks[r]); y[r] = fmaf(hsubh, fr, h[r]); }
            else if (e == 2) { ks[r] = fmaf(2.0f, fr, ks[r]); y[r] = fmaf(hsub,  fr, h[r]); }
            else             { ks[r] += fr; h[r] = fmaf(h6, ks[r], h[r]); y[r] = h[r]; }
        }
        unsigned t01 = pk(fast_tanh(y[0]), fast_tanh(y[1]));
        unsigned t23 = pk(fast_tanh(y[2]), fast_tanh(y[3]));
        unsigned char* bp = tbuf[p];
        *(uint2*)(bp + woff) = make_uint2(t01, t23);
        __syncthreads();
        B0 = __builtin_bit_cast(half8, *(const uint4*)(bp + roff0));
        B1 = __builtin_bit_cast(half8, *(const uint4*)(bp + roff1));
        p ^= 1;
    };

    // prefetch x for s=1
    float4 xp0 = xrow[4], xp1 = xrow[5], xp2 = xrow[6], xp3 = xrow[7];

    for (int s = 1; s < SLEN; ++s) {
        // cr[r] = (x_s . Wc_rt[r]) + cbase_rt[r]  (f32, off critical path)
        #pragma unroll
        for (int r = 0; r < 4; ++r) {
            float cA = fmaf(xp0.x, Wc_rt[r][0], fmaf(xp0.y, Wc_rt[r][1],
                       fmaf(xp0.z, Wc_rt[r][2], fmaf(xp0.w, Wc_rt[r][3], cbase_rt[r]))));
            float cB = fmaf(xp1.x, Wc_rt[r][4], fmaf(xp1.y, Wc_rt[r][5],
                       fmaf(xp1.z, Wc_rt[r][6], xp1.w * Wc_rt[r][7])));
            float cC = fmaf(xp2.x, Wc_rt[r][8], fmaf(xp2.y, Wc_rt[r][9],
                       fmaf(xp2.z, Wc_rt[r][10], xp2.w * Wc_rt[r][11])));
            float cD = fmaf(xp3.x, Wc_rt[r][12], fmaf(xp3.y, Wc_rt[r][13],
                       fmaf(xp3.z, Wc_rt[r][14], xp3.w * Wc_rt[r][15])));
            cr[r] = (cA + cB) + (cC + cD);
        }
        // prefetch next step's x (hidden behind 16 bodies)
        {
            int sn = (s < SLEN - 1) ? (s + 1) : (SLEN - 1);
            xp0 = xrow[sn*4+0]; xp1 = xrow[sn*4+1];
            xp2 = xrow[sn*4+2]; xp3 = xrow[sn*4+3];
        }

        #pragma unroll 1
        for (int sub = 0; sub < 4; ++sub) {
            body(0, sub == 0, s);        // k1 (+ fused out[s-1]; s=1 -> out[0]=bo)
            body(1, false, s);           // k2
            body(2, false, s);           // k3
            body(3, false, s);           // k4 + h update
        }
    }

    // epilogue: B-frags hold tanh(h_1023) -> out[1023]
    {
        uint4 b0 = __builtin_bit_cast(uint4, B0);
        uint4 b1 = __builtin_bit_cast(uint4, B1);
        float o;
        o = __builtin_amdgcn_fdot2(__builtin_bit_cast(h2_t, b0.x), wo0[0], 0.0f, false);
        o = __builtin_amdgcn_fdot2(__builtin_bit_cast(h2_t, b0.y), wo0[1], o, false);
        o = __builtin_amdgcn_fdot2(__builtin_bit_cast(h2_t, b0.z), wo0[2], o, false);
        o = __builtin_amdgcn_fdot2(__builtin_bit_cast(h2_t, b0.w), wo0[3], o, false);
        o = __builtin_amdgcn_fdot2(__builtin_bit_cast(h2_t, b1.x), wo1[0], o, false);
        o = __builtin_amdgcn_fdot2(__builtin_bit_cast(h2_t, b1.y), wo1[1], o, false);
        o = __builtin_amdgcn_fdot2(__builtin_bit_cast(h2_t, b1.z), wo1[2], o, false);
        o = __builtin_amdgcn_fdot2(__builtin_bit_cast(h2_t, b1.w), wo1[3], o, false);
        o += __shfl_xor(o, 16, 64);
        o += __shfl_xor(o, 32, 64);
        if (tid < 16) out[(size_t)(blockIdx.x*16 + tid) * SLEN + (SLEN-1)] = o + bo;
    }
    (void)orow;
}

extern "C" void kernel_launch(void* const* d_in, const int* in_sizes, int n_in,
                              void* d_out, int out_size, void* d_ws, size_t ws_size,
                              hipStream_t stream) {
    const float* x     = (const float*)d_in[0];
    const float* W_in  = (const float*)d_in[1];
    const float* b_in  = (const float*)d_in[2];
    const float* W_hh  = (const float*)d_in[3];
    const float* W_ih  = (const float*)d_in[4];
    const float* bias  = (const float*)d_in[5];
    const float* tau   = (const float*)d_in[6];
    const float* W_out = (const float*)d_in[7];
    const float* b_out = (const float*)d_in[8];
    float* out = (float*)d_out;

    lnn_mfma_kernel<<<32, 256, 0, stream>>>(x, W_in, b_in, W_hh, W_ih, bias,
                                            tau, W_out, b_out, out);
}